// Round 12
// baseline (541.289 us; speedup 1.0000x reference)
//
#include <hip/hip_runtime.h>
#include <cstdint>
#include <cstddef>

#define TSTEPS 512
#define INP    24
#define HID    128
#define BB     4      // batch elems per block; 256 blocks (1/CU)
#define NKT    5      // K = 128 h + 24 x + 8 pad = 160 = 5 tiles of 32
#define VSTR   168    // v[] column stride in fp16 elems: [h 0..127 | x 128..151 | pad]
#define NTHR   256    // 4 fat compute waves, 1 per SIMD

typedef __attribute__((ext_vector_type(8))) _Float16 half8;   // 8 x fp16 (4 VGPRs)
typedef __attribute__((ext_vector_type(4))) float f32x4;

__device__ __forceinline__ float rcp_f(float v) { return __builtin_amdgcn_rcpf(v); }
__device__ __forceinline__ float sigm_f(float v) {
    return rcp_f(1.0f + __expf(-v));
}
__device__ __forceinline__ float tanh_f(float v) {
    return 1.0f - 2.0f * rcp_f(1.0f + __expf(2.0f * v));
}
__device__ __forceinline__ unsigned pack2h(float a, float b) {
    union { _Float16 h[2]; unsigned u; } z;
    z.h[0] = (_Float16)a; z.h[1] = (_Float16)b;   // v_cvt_f16_f32, RTN
    return z.u;
}
// select a[r] with r = 2*rb1 + rb0; compile-time component indices (R2-safe)
__device__ __forceinline__ float sel4(const f32x4 a, bool rb0, bool rb1) {
    const float lo = rb0 ? a[1] : a[0];
    const float hi = rb0 ? a[3] : a[2];
    return rb1 ? hi : lo;
}

// ROUND LESSONS ENCODED:
//  R1: VGPR-cap betrayal -> scratch spill shows as WRITE_SIZE GBs.
//  R2: runtime-varying index into per-thread arrays demotes to memory
//      (fully-unrolled loop indices are compile-time -> OK).
//  R3: fp32 VALU ~3x too slow; use MFMA.
//  R4/R5: total time == per-block time. MINIMIZE BLOCK WALL (= max over waves).
//  R6: mfma issue ~19.4 cyc/SIMD; 160 mfma/block/ts invariant -> 776
//      cyc/SIMD floor REGARDLESS of wave count (total work / 4 SIMDs).
//  R8: LDS pipe is PER-CU.
//  R9: single-pass fp16 weights/state; absmax ~2^-11.
//  R10: wave-local redistribution, ONE barrier/ts: 619->542us.
//  R11/R12/R13: occupancy attrs with SMALL caps spill; HW won't co-schedule
//      2 blocks/CU. (1,1) = cap 512 is the SAFE direction.
//  R14: phases SUM within a wave (serial chain).
//  R15: elementwise on 16 lanes = 4x issue tax. Keep all lanes busy.
//  R16: bias->C-init + rcp sigm/tanh + pre-barrier x-tile: 542->453us.
//  R17: exec-masked B-reads regressed. LDS pipe NOT critical path.
//  R18: replica columns -> redistribution = 12 cndmask, part_s deleted: ->403us.
//  R19: uniform wave paths (dedicated stager, acc->C-in, hoisted reads):
//      403->337us (rocprof). MfmaUtil 45 = 716cyc ~ the 776 floor; wall
//      1581 = floor + ~800 of chain + 2-wave/SIMD lockstep contention.
//  R20 (this): 4 FAT WAVES, 1/SIMD. Each wave: 2 M-tiles (32 units), 8
//      independent chains x 5 mfma = 40 mfma; 2 cells/lane update;
//      x-staging spread uniformly (wave wv stages batch wv, 12 lanes).
//      Same 776 floor, zero issue contention, no lockstep. VGPR ~300
//      (A_w 160 + acc/bias ~100) -> waves_per_eu(1,1) caps at 512, no
//      spill expected. Predict 260-300us rocprof, MfmaUtil 52-62,
//      conflicts ~1.1e7, WRITE_SIZE ~16B (kill-switch).
//      Falsifier: dur >= 337 no-spill -> latency exposure > contention
//      -> revert to R19 shape + setprio.
//
// Per ts: gates[512 x 4] = W[512 x 160] @ v[160 x 4], broadcast to 16 cols.
// mfma_f32_16x16x32_f16:
//   A-frag: lane holds A[m=lane&15][k=quad*8+j]
//   B-frag: lane holds B[k=quad*8+j][n=lane&15]
//   C/D:    col=lane&15, row=quad*4+reg
__global__ __launch_bounds__(NTHR) __attribute__((amdgpu_waves_per_eu(1, 1)))
void lstm_fused(
    const float* __restrict__ x,      // [B, T, 24]
    const float* __restrict__ addin,  // [B, 2]
    const float* __restrict__ W_ih,   // [512, 24]
    const float* __restrict__ W_hh,   // [512, 128]
    const float* __restrict__ b_ih,   // [512]
    const float* __restrict__ b_hh,   // [512]
    const float* __restrict__ W1,     // [64, 130]
    const float* __restrict__ b1,     // [64]
    const float* __restrict__ W2,     // [3, 64]
    const float* __restrict__ b2,     // [3]
    float* __restrict__ out)          // [B, 3]
{
    __shared__ _Float16 v_s[2][BB * VSTR];   // [buf][col<4][k']; k'<128 h, 128..151 x
    __shared__ float z_s[BB][64];

    const int t    = threadIdx.x;      // 256 threads = 4 waves
    const int lane = t & 63;
    const int wv   = t >> 6;           // 0..3: owns unit rows [wv*32, wv*32+32)
    const int ncol = lane & 15;
    const int quad = lane >> 4;
    const int b0   = blockIdx.x * BB;
    const int bsel = ncol & 3;         // broadcast source col = this lane's batch
    const bool rb0 = (ncol >> 2) & 1;  // reg-select bits: r = ncol>>2
    const bool rb1 = (ncol >> 3) & 1;

    // ---- persistent A-fragments: 2 M-tiles x 4 gates x 5 K-tiles ----
    half8 A_w[2][4][NKT];
    #pragma unroll
    for (int m = 0; m < 2; ++m) {
        #pragma unroll
        for (int g = 0; g < 4; ++g) {
            const int row = g * HID + wv * 32 + m * 16 + ncol;
            #pragma unroll
            for (int kt = 0; kt < NKT; ++kt) {
                half8 frag;
                #pragma unroll
                for (int j = 0; j < 8; ++j) {
                    const int k = kt * 32 + quad * 8 + j;
                    float w = 0.0f;
                    if (k < HID)            w = W_hh[row * HID + k];
                    else if (k < HID + INP) w = W_ih[row * INP + (k - HID)];
                    frag[j] = (_Float16)w;
                }
                A_w[m][g][kt] = frag;
            }
        }
    }

    // bias as mfma C-init
    f32x4 biasv[2][4];
    #pragma unroll
    for (int m = 0; m < 2; ++m) {
        #pragma unroll
        for (int g = 0; g < 4; ++g) {
            #pragma unroll
            for (int r = 0; r < 4; ++r) {
                const int u = wv * 32 + m * 16 + quad * 4 + r;
                biasv[m][g][r] = b_ih[g * HID + u] + b_hh[g * HID + u];
            }
        }
    }

    // cell ownership: 2 cells/lane (one per M-tile), batch bsel
    const int uj0 = wv * 32 + quad * 4 + (ncol >> 2);   // m=0; m=1 is uj0+16
    float creg[2] = {0.f, 0.f};

    // x-staging role (UNIFORM): wave wv stages batch col wv, lanes 0..11
    const int kk = lane;               // k-pair index (lanes < 12)
    const size_t xrow = (size_t)(b0 + wv) * TSTEPS;

    // ---- init: zero both buffers (B1) ----
    for (int i = t; i < BB * VSTR; i += NTHR) {
        v_s[0][i] = (_Float16)0.0f; v_s[1][i] = (_Float16)0.0f;
    }
    __syncthreads();   // B1

    float2 xq = {0.f, 0.f};
    if (lane < 12) {
        const float2 x0 = *(const float2*)(x + (xrow + 0) * INP + kk * 2);
        const float2 x1 = *(const float2*)(x + (xrow + 1) * INP + kk * 2);
        *(unsigned*)&v_s[0][wv * VSTR + HID + kk * 2] = pack2h(x0.x, x0.y);
        *(unsigned*)&v_s[1][wv * VSTR + HID + kk * 2] = pack2h(x1.x, x1.y);
        xq = *(const float2*)(x + (xrow + 2) * INP + kk * 2);
    }
    __syncthreads();   // B2: x(0), x(1) visible

    // prologue: x-tile mfma for ts=0 from buf0, C-init = bias
    f32x4 ac[2][4];
    {
        const half8 bx0 = *(const half8*)(&v_s[0][0] + bsel * VSTR + HID + quad * 8);
        #pragma unroll
        for (int m = 0; m < 2; ++m)
            #pragma unroll
            for (int g = 0; g < 4; ++g)
                ac[m][g] = __builtin_amdgcn_mfma_f32_16x16x32_f16(
                    A_w[m][g][4], bx0, biasv[m][g], 0, 0, 0);
    }
    __syncthreads();   // B3: protect buf0 x-region before iter0 overwrites

    // ---- recurrence: ONE barrier per ts ----
    #pragma unroll 2
    for (int ts = 0; ts < TSTEPS; ++ts) {
        const int pb = ts & 1, nb = pb ^ 1;

        // staging (uniform across waves): write x(ts+2) into pb; load x(ts+3)
        float2 xn = {0.f, 0.f};
        if (lane < 12) {
            const int tsn = (ts + 3 < TSTEPS) ? ts + 3 : TSTEPS - 1;
            xn = *(const float2*)(x + (xrow + tsn) * INP + kk * 2);
            *(unsigned*)&v_s[pb][wv * VSTR + HID + kk * 2] = pack2h(xq.x, xq.y);
        }

        // hoist all B-frag reads (latency under mfma ramp)
        const _Float16* vh = v_s[pb];
        half8 bh[4];
        #pragma unroll
        for (int kt = 0; kt < 4; ++kt)
            bh[kt] = *(const half8*)(vh + bsel * VSTR + kt * 32 + quad * 8);
        const half8 bx = *(const half8*)(&v_s[nb][0] + bsel * VSTR + HID + quad * 8);

        // h-GEMM: 8 independent chains x 4 kt; carried acc feeds kt0 C-in
        f32x4 a[2][4];
        #pragma unroll
        for (int m = 0; m < 2; ++m)
            #pragma unroll
            for (int g = 0; g < 4; ++g)
                a[m][g] = __builtin_amdgcn_mfma_f32_16x16x32_f16(
                    A_w[m][g][0], bh[0], ac[m][g], 0, 0, 0);
        #pragma unroll
        for (int kt = 1; kt < 4; ++kt)
            #pragma unroll
            for (int m = 0; m < 2; ++m)
                #pragma unroll
                for (int g = 0; g < 4; ++g)
                    a[m][g] = __builtin_amdgcn_mfma_f32_16x16x32_f16(
                        A_w[m][g][kt], bh[kt], a[m][g], 0, 0, 0);

        // in-register redistribution: this lane's 2 cells (reg r = ncol>>2)
        float s[2][4];
        #pragma unroll
        for (int m = 0; m < 2; ++m)
            #pragma unroll
            for (int g = 0; g < 4; ++g)
                s[m][g] = sel4(a[m][g], rb0, rb1);

        // next-ts x-tile mfma (independent; overlaps trans tail on mfma pipe)
        #pragma unroll
        for (int m = 0; m < 2; ++m)
            #pragma unroll
            for (int g = 0; g < 4; ++g)
                ac[m][g] = __builtin_amdgcn_mfma_f32_16x16x32_f16(
                    A_w[m][g][4], bx, biasv[m][g], 0, 0, 0);

        // cell updates: 2 cells per lane, all 64 lanes busy
        #pragma unroll
        for (int m = 0; m < 2; ++m) {
            const float gi = sigm_f(s[m][0]);
            const float gf = sigm_f(s[m][1]);
            const float gg = tanh_f(s[m][2]);
            const float go = sigm_f(s[m][3]);
            creg[m] = gf * creg[m] + gi * gg;
            const float h = go * tanh_f(creg[m]);
            v_s[nb][bsel * VSTR + uj0 + m * 16] = (_Float16)h;
        }

        // roll x queue
        if (lane < 12) xq = xn;

        // single cross-wave hazard: h(ts) + x(ts+2) visible next epoch
        __syncthreads();
    }

    // ---- FC head: final h is in buffer 0 (ts=511 -> nb=0), offset 0..127 ----
    {
        const int b = t >> 6, u = t & 63;
        const float* w = W1 + u * 130;
        float a = b1[u];
        #pragma unroll 16
        for (int k = 0; k < HID; ++k) {
            const float hv = (float)v_s[0][b * VSTR + k];
            a += fmaxf(hv, 0.0f) * w[k];
        }
        const float a0 = addin[(size_t)(b0 + b) * 2 + 0];
        const float a1 = addin[(size_t)(b0 + b) * 2 + 1];
        a += fmaxf(a0, 0.0f) * w[128] + fmaxf(a1, 0.0f) * w[129];
        z_s[b][u] = fmaxf(a, 0.0f);
    }
    __syncthreads();
    if (t < 3 * BB) {
        const int b = t / 3, o = t - 3 * b;
        const float* w = W2 + o * 64;
        float a = b2[o];
        #pragma unroll
        for (int k = 0; k < 64; ++k)
            a += z_s[b][k] * w[k];
        out[(size_t)(b0 + b) * 3 + o] = a;
    }
}

extern "C" void kernel_launch(void* const* d_in, const int* in_sizes, int n_in,
                              void* d_out, int out_size, void* d_ws, size_t ws_size,
                              hipStream_t stream) {
    const float* x     = (const float*)d_in[0];
    const float* addin = (const float*)d_in[1];
    const float* W_ih  = (const float*)d_in[2];
    const float* W_hh  = (const float*)d_in[3];
    const float* b_ih  = (const float*)d_in[4];
    const float* b_hh  = (const float*)d_in[5];
    const float* W1    = (const float*)d_in[6];
    const float* b1    = (const float*)d_in[7];
    const float* W2    = (const float*)d_in[8];
    const float* b2    = (const float*)d_in[9];
    float* outp        = (float*)d_out;

    const int B = in_sizes[0] / (TSTEPS * INP);   // 1024
    const int grid = B / BB;                      // 256 blocks (1 per CU)

    lstm_fused<<<grid, NTHR, 0, stream>>>(x, addin, W_ih, W_hh, b_ih, b_hh,
                                          W1, b1, W2, b2, outp);
}

// Round 13
// 367.081 us; speedup vs baseline: 1.4746x; 1.4746x over previous
//
#include <hip/hip_runtime.h>
#include <cstdint>
#include <cstddef>

#define TSTEPS 512
#define INP    24
#define HID    128
#define BB     4      // batch elems per block; 256 blocks (1/CU)
#define NKT    5      // K = 128 h + 24 x + 8 pad = 160 = 5 tiles of 32
#define VSTR   168    // v[] column stride in fp16 elems: [h 0..127 | x 128..151 | pad]
#define NTHR   576    // 8 compute waves + 1 dedicated staging wave

typedef __attribute__((ext_vector_type(8))) _Float16 half8;   // 8 x fp16 (4 VGPRs)
typedef __attribute__((ext_vector_type(4))) float f32x4;

__device__ __forceinline__ float rcp_f(float v) { return __builtin_amdgcn_rcpf(v); }
__device__ __forceinline__ float sigm_f(float v) {
    return rcp_f(1.0f + __expf(-v));
}
__device__ __forceinline__ float tanh_f(float v) {
    return 1.0f - 2.0f * rcp_f(1.0f + __expf(2.0f * v));
}
__device__ __forceinline__ unsigned pack2h(float a, float b) {
    union { _Float16 h[2]; unsigned u; } z;
    z.h[0] = (_Float16)a; z.h[1] = (_Float16)b;   // v_cvt_f16_f32, RTN
    return z.u;
}
// select a[r] with r = 2*rb1 + rb0; compile-time component indices (R2-safe)
__device__ __forceinline__ float sel4(const f32x4 a, bool rb0, bool rb1) {
    const float lo = rb0 ? a[1] : a[0];
    const float hi = rb0 ? a[3] : a[2];
    return rb1 ? hi : lo;
}

// ROUND LESSONS ENCODED:
//  R1: VGPR-cap betrayal -> scratch spill shows as WRITE_SIZE GBs (per-ts).
//      One-time ~10s of MB = setup spill, benign.
//  R2: runtime-varying index into per-thread arrays demotes to memory.
//  R3: fp32 VALU ~3x too slow; use MFMA.
//  R4/R5: total time == per-block time. MINIMIZE BLOCK WALL (= max over waves).
//  R6: mfma issue ~19.4 cyc/SIMD; 160 mfma/block/ts -> 776 cyc/SIMD floor.
//  R8: LDS pipe is PER-CU.  R9: fp16 single-pass; absmax ~2^-11.
//  R10: wave-local redistribution, ONE barrier/ts: 619->542us.
//  R11/R12/R13: occupancy attrs spill; HW won't co-schedule 2 blocks/CU.
//  R14: phases SUM within a wave.  R15: keep elementwise on all 64 lanes.
//  R16: bias->C-init + rcp sigm/tanh + pre-barrier x-tile: 542->453us.
//  R17: exec-masked B-reads regressed; LDS pipe NOT critical path.
//  R18: replica columns -> redistribution = 12 cndmask: ->403us.
//  R19: uniform wave paths (dedicated stager, acc->C-in, hoisted reads):
//      403->337us (rocprof). MfmaUtil 45; wall 1581 = 776 floor + chain.
//  R20: 4 fat waves 1/SIMD: 544us. 1 wave/SIMD exposes ALL latency; the
//      2-wave "contention" in R19 WAS the latency hiding. Reverted.
//  R21 (this): FILL THE POST-BARRIER LATENCY HOLE. Hold x-frag in regs
//      across the barrier; issue the 4 x-tile mfma at phase TOP (right
//      after the 5 ds_read issue) so they execute inside the ~120cyc
//      read-latency window, with results ready as kt0's C-in when bh0
//      lands. setprio(1) around the 16-mfma h-GEMM. Stager skips A_w/bias
//      load (moved into compute branch). Arithmetic identical -> absmax
//      must stay 0.0004882812. Predict rocprof 337->305-325, MfmaUtil
//      47-51. Falsifier: <5us -> hole already covered; structural floor.
//
// Per ts: gates[512 x 4] = W[512 x 160] @ v[160 x 4], broadcast to 16 cols.
// mfma_f32_16x16x32_f16:
//   A-frag: lane holds A[m=lane&15][k=quad*8+j]
//   B-frag: lane holds B[k=quad*8+j][n=lane&15]
//   C/D:    col=lane&15, row=quad*4+reg
__global__ __launch_bounds__(NTHR)
void lstm_fused(
    const float* __restrict__ x,      // [B, T, 24]
    const float* __restrict__ addin,  // [B, 2]
    const float* __restrict__ W_ih,   // [512, 24]
    const float* __restrict__ W_hh,   // [512, 128]
    const float* __restrict__ b_ih,   // [512]
    const float* __restrict__ b_hh,   // [512]
    const float* __restrict__ W1,     // [64, 130]
    const float* __restrict__ b1,     // [64]
    const float* __restrict__ W2,     // [3, 64]
    const float* __restrict__ b2,     // [3]
    float* __restrict__ out)          // [B, 3]
{
    __shared__ _Float16 v_s[2][BB * VSTR];   // [buf][col<4][k']; k'<128 h, 128..151 x
    __shared__ float z_s[BB][64];

    const int t    = threadIdx.x;      // 576 threads = 9 waves
    const int lane = t & 63;
    const int wv   = t >> 6;           // 0..8; wave 8 = stager
    const bool is_stage = (wv == 8);
    const int ncol = lane & 15;
    const int quad = lane >> 4;
    const int b0   = blockIdx.x * BB;
    const int bsel = ncol & 3;         // broadcast source col = this lane's batch
    const bool rb0 = (ncol >> 2) & 1;  // reg-select bits: r = ncol>>2
    const bool rb1 = (ncol >> 3) & 1;

    // staging-wave role: lane sb = lane/12 (batch col), kk (k-pair); 48 active
    const int sb = lane / 12;
    const int kk = lane - sb * 12;
    const size_t xrow = (size_t)(b0 + (sb & 3)) * TSTEPS;

    // ---- init: zero both buffers (B1) ----
    for (int i = t; i < BB * VSTR; i += NTHR) {
        v_s[0][i] = (_Float16)0.0f; v_s[1][i] = (_Float16)0.0f;
    }
    __syncthreads();   // B1

    if (is_stage) {
        // ============ STAGING WAVE (never touches W) ============
        float2 xq = {0.f, 0.f};
        if (lane < 48) {
            const float2 x0 = *(const float2*)(x + (xrow + 0) * INP + kk * 2);
            const float2 x1 = *(const float2*)(x + (xrow + 1) * INP + kk * 2);
            *(unsigned*)&v_s[0][sb * VSTR + HID + kk * 2] = pack2h(x0.x, x0.y);
            *(unsigned*)&v_s[1][sb * VSTR + HID + kk * 2] = pack2h(x1.x, x1.y);
            xq = *(const float2*)(x + (xrow + 2) * INP + kk * 2);
        }
        __syncthreads();   // B2: x(0),x(1) visible to compute waves
        __syncthreads();   // B3: compute waves captured buf0 x-region
        for (int ts = 0; ts < TSTEPS; ++ts) {
            const int pb = ts & 1;
            if (lane < 48) {
                const int tsn = (ts + 3 < TSTEPS) ? ts + 3 : TSTEPS - 1;
                const float2 xn = *(const float2*)(x + (xrow + tsn) * INP + kk * 2);
                *(unsigned*)&v_s[pb][sb * VSTR + HID + kk * 2] = pack2h(xq.x, xq.y);
                xq = xn;
            }
            __syncthreads();
        }
    } else {
        // ============ COMPUTE WAVES ============
        // persistent A-fragments (fp16), k' layout: [W_hh | W_ih | 0]
        half8 A_w[4][NKT];
        #pragma unroll
        for (int g = 0; g < 4; ++g) {
            const int row = g * HID + wv * 16 + ncol;
            #pragma unroll
            for (int kt = 0; kt < NKT; ++kt) {
                half8 frag;
                #pragma unroll
                for (int j = 0; j < 8; ++j) {
                    const int k = kt * 32 + quad * 8 + j;
                    float w = 0.0f;
                    if (k < HID)            w = W_hh[row * HID + k];
                    else if (k < HID + INP) w = W_ih[row * INP + (k - HID)];
                    frag[j] = (_Float16)w;
                }
                A_w[g][kt] = frag;
            }
        }
        // bias as mfma C-init
        f32x4 biasv[4];
        #pragma unroll
        for (int g = 0; g < 4; ++g) {
            #pragma unroll
            for (int r = 0; r < 4; ++r) {
                const int u = wv * 16 + quad * 4 + r;
                biasv[g][r] = b_ih[g * HID + u] + b_hh[g * HID + u];
            }
        }
        const int uj = wv * 16 + quad * 4 + (ncol >> 2);
        float c_reg = 0.0f;

        __syncthreads();   // B2: x(0), x(1) staged

        // capture x(0) fragment into regs (survives stager's overwrite)
        half8 bxh = *(const half8*)(&v_s[0][0] + bsel * VSTR + HID + quad * 8);
        __syncthreads();   // B3: stager may now overwrite buf0 x-region

        #pragma unroll 2
        for (int ts = 0; ts < TSTEPS; ++ts) {
            const int pb = ts & 1, nb = pb ^ 1;
            const _Float16* vh = v_s[pb];

            // 1. issue all ds_reads first (latency clock starts)
            const half8 bh0 = *(const half8*)(vh + bsel * VSTR + 0 * 32 + quad * 8);
            const half8 bh1 = *(const half8*)(vh + bsel * VSTR + 1 * 32 + quad * 8);
            const half8 bh2 = *(const half8*)(vh + bsel * VSTR + 2 * 32 + quad * 8);
            const half8 bh3 = *(const half8*)(vh + bsel * VSTR + 3 * 32 + quad * 8);
            const half8 bxn = *(const half8*)(&v_s[nb][0] + bsel * VSTR + HID + quad * 8);

            // 2. x-tile mfma for THIS ts from bxh (held since last phase):
            //    executes inside the read-latency window; result = kt0 C-in.
            const f32x4 aci = __builtin_amdgcn_mfma_f32_16x16x32_f16(A_w[0][4], bxh, biasv[0], 0, 0, 0);
            const f32x4 acf = __builtin_amdgcn_mfma_f32_16x16x32_f16(A_w[1][4], bxh, biasv[1], 0, 0, 0);
            const f32x4 acg = __builtin_amdgcn_mfma_f32_16x16x32_f16(A_w[2][4], bxh, biasv[2], 0, 0, 0);
            const f32x4 aco = __builtin_amdgcn_mfma_f32_16x16x32_f16(A_w[3][4], bxh, biasv[3], 0, 0, 0);

            // 3. h-GEMM: 4 chains x 4 kt; carried acc feeds kt0 C-in
            __builtin_amdgcn_s_setprio(1);
            f32x4 ai = __builtin_amdgcn_mfma_f32_16x16x32_f16(A_w[0][0], bh0, aci, 0, 0, 0);
            f32x4 af = __builtin_amdgcn_mfma_f32_16x16x32_f16(A_w[1][0], bh0, acf, 0, 0, 0);
            f32x4 ag = __builtin_amdgcn_mfma_f32_16x16x32_f16(A_w[2][0], bh0, acg, 0, 0, 0);
            f32x4 ao = __builtin_amdgcn_mfma_f32_16x16x32_f16(A_w[3][0], bh0, aco, 0, 0, 0);
            ai = __builtin_amdgcn_mfma_f32_16x16x32_f16(A_w[0][1], bh1, ai, 0, 0, 0);
            af = __builtin_amdgcn_mfma_f32_16x16x32_f16(A_w[1][1], bh1, af, 0, 0, 0);
            ag = __builtin_amdgcn_mfma_f32_16x16x32_f16(A_w[2][1], bh1, ag, 0, 0, 0);
            ao = __builtin_amdgcn_mfma_f32_16x16x32_f16(A_w[3][1], bh1, ao, 0, 0, 0);
            ai = __builtin_amdgcn_mfma_f32_16x16x32_f16(A_w[0][2], bh2, ai, 0, 0, 0);
            af = __builtin_amdgcn_mfma_f32_16x16x32_f16(A_w[1][2], bh2, af, 0, 0, 0);
            ag = __builtin_amdgcn_mfma_f32_16x16x32_f16(A_w[2][2], bh2, ag, 0, 0, 0);
            ao = __builtin_amdgcn_mfma_f32_16x16x32_f16(A_w[3][2], bh2, ao, 0, 0, 0);
            ai = __builtin_amdgcn_mfma_f32_16x16x32_f16(A_w[0][3], bh3, ai, 0, 0, 0);
            af = __builtin_amdgcn_mfma_f32_16x16x32_f16(A_w[1][3], bh3, af, 0, 0, 0);
            ag = __builtin_amdgcn_mfma_f32_16x16x32_f16(A_w[2][3], bh3, ag, 0, 0, 0);
            ao = __builtin_amdgcn_mfma_f32_16x16x32_f16(A_w[3][3], bh3, ao, 0, 0, 0);
            __builtin_amdgcn_s_setprio(0);

            // 4. in-register redistribution + cell update (all 64 lanes)
            const float si = sel4(ai, rb0, rb1);
            const float sf = sel4(af, rb0, rb1);
            const float sg = sel4(ag, rb0, rb1);
            const float so = sel4(ao, rb0, rb1);
            {
                const float gi = sigm_f(si);
                const float gf = sigm_f(sf);
                const float gg = tanh_f(sg);
                const float go = sigm_f(so);
                c_reg = gf * c_reg + gi * gg;
                const float h = go * tanh_f(c_reg);
                v_s[nb][bsel * VSTR + uj] = (_Float16)h;
            }

            // 5. roll held x-frag
            bxh = bxn;

            // single cross-wave hazard: h(ts) + x(ts+2) visible next epoch
            __syncthreads();
        }
    }

    // ---- FC head: final h is in buffer 0 (ts=511 -> nb=0), offset 0..127 ----
    if (t < 64 * BB) {
        const int b = t >> 6, u = t & 63;
        const float* w = W1 + u * 130;
        float a = b1[u];
        #pragma unroll 16
        for (int k = 0; k < HID; ++k) {
            const float hv = (float)v_s[0][b * VSTR + k];
            a += fmaxf(hv, 0.0f) * w[k];
        }
        const float a0 = addin[(size_t)(b0 + b) * 2 + 0];
        const float a1 = addin[(size_t)(b0 + b) * 2 + 1];
        a += fmaxf(a0, 0.0f) * w[128] + fmaxf(a1, 0.0f) * w[129];
        z_s[b][u] = fmaxf(a, 0.0f);
    }
    __syncthreads();
    if (t < 3 * BB) {
        const int b = t / 3, o = t - 3 * b;
        const float* w = W2 + o * 64;
        float a = b2[o];
        #pragma unroll
        for (int k = 0; k < 64; ++k)
            a += z_s[b][k] * w[k];
        out[(size_t)(b0 + b) * 3 + o] = a;
    }
}

extern "C" void kernel_launch(void* const* d_in, const int* in_sizes, int n_in,
                              void* d_out, int out_size, void* d_ws, size_t ws_size,
                              hipStream_t stream) {
    const float* x     = (const float*)d_in[0];
    const float* addin = (const float*)d_in[1];
    const float* W_ih  = (const float*)d_in[2];
    const float* W_hh  = (const float*)d_in[3];
    const float* b_ih  = (const float*)d_in[4];
    const float* b_hh  = (const float*)d_in[5];
    const float* W1    = (const float*)d_in[6];
    const float* b1    = (const float*)d_in[7];
    const float* W2    = (const float*)d_in[8];
    const float* b2    = (const float*)d_in[9];
    float* outp        = (float*)d_out;

    const int B = in_sizes[0] / (TSTEPS * INP);   // 1024
    const int grid = B / BB;                      // 256 blocks (1 per CU)

    lstm_fused<<<grid, NTHR, 0, stream>>>(x, addin, W_ih, W_hh, b_ih, b_hh,
                                          W1, b1, W2, b2, outp);
}